// Round 1
// baseline (1142.495 us; speedup 1.0000x reference)
//
#include <hip/hip_runtime.h>
#include <stdint.h>
#include <math.h>

// ---------------- Threefry-2x32 (JAX-compatible, 20 rounds) ----------------
__host__ __device__ static inline uint32_t rotl32(uint32_t v, uint32_t d) {
  return (v << d) | (v >> (32u - d));
}

struct U2 { uint32_t a, b; };

__host__ __device__ static inline U2 tf2x32(uint32_t k0, uint32_t k1,
                                            uint32_t x0, uint32_t x1) {
  const uint32_t k2 = k0 ^ k1 ^ 0x1BD11BDAu;
  x0 += k0; x1 += k1;
#define TF_R(rot) { x0 += x1; x1 = rotl32(x1, rot); x1 ^= x0; }
  TF_R(13u) TF_R(15u) TF_R(26u) TF_R(6u)
  x0 += k1; x1 += k2 + 1u;
  TF_R(17u) TF_R(29u) TF_R(16u) TF_R(24u)
  x0 += k2; x1 += k0 + 2u;
  TF_R(13u) TF_R(15u) TF_R(26u) TF_R(6u)
  x0 += k0; x1 += k1 + 3u;
  TF_R(17u) TF_R(29u) TF_R(16u) TF_R(24u)
  x0 += k1; x1 += k2 + 4u;
  TF_R(13u) TF_R(15u) TF_R(26u) TF_R(6u)
  x0 += k2; x1 += k0 + 5u;
#undef TF_R
  U2 r; r.a = x0; r.b = x1; return r;
}

// Partitionable random bits: bits[i] = y0 ^ y1 of TF(key, (0, i));
// uniform[0,1): bitcast((bits>>9)|0x3f800000) - 1
__device__ static inline float tf_unif(uint32_t k0, uint32_t k1, uint32_t idx) {
  U2 r = tf2x32(k0, k1, 0u, idx);
  uint32_t bits = r.a ^ r.b;
  return __uint_as_float((bits >> 9) | 0x3f800000u) - 1.0f;
}

// -------- kernel 1: even-even copy + diamond (odd,odd) sites --------
__global__ void ds_k1(const float* __restrict__ src, float* __restrict__ dst,
                      int H, int W, int nH, int nW,
                      const float* __restrict__ dk,
                      const float* __restrict__ scale_p,
                      uint32_t kd0, uint32_t kd1) {
  int idx = blockIdx.x * blockDim.x + threadIdx.x;
  int total = 4 * nH * nW;
  if (idx >= total) return;
  int j = idx % nW;
  int t = idx / nW;
  int i = t % nH;
  int b = t / nH;
  int pi = i & 1, pj = j & 1;
  if (pi == 0 && pj == 0) {
    dst[idx] = src[(b * H + (i >> 1)) * W + (j >> 1)];
  } else if (pi == 1 && pj == 1) {
    int r0 = (i - 1) >> 1, c0 = (j - 1) >> 1;
    const float* s0 = src + (b * H + r0) * W + c0;
    float v00 = s0[0];
    float v01 = s0[1];
    float v10 = s0[W];
    float v11 = s0[W + 1];
    // cross-correlation taps at (i-1,j-1),(i-1,j+1),(i+1,j-1),(i+1,j+1)
    float d = dk[0] * v00 + dk[2] * v01 + dk[6] * v10 + dk[8] * v11;
    int Hd = H - 1, Wd = W - 1;
    uint32_t nidx = (uint32_t)((b * Hd + r0) * Wd + c0);
    float u = tf_unif(kd0, kd1, nidx);
    dst[idx] = d + (u - 0.5f) * scale_p[0];
  }
  // square sites written by ds_k2
}

// -------- kernel 2: square ((i+j) odd) sites, in-place --------
// Reads only even-parity sites, writes only odd-parity: race-free in-place.
__global__ void ds_k2(float* __restrict__ img, int nH, int nW,
                      const float* __restrict__ sk,
                      const float* __restrict__ scale_p,
                      uint32_t ks0, uint32_t ks1) {
  int idx = blockIdx.x * blockDim.x + threadIdx.x;
  int total = 4 * nH * nW;
  if (idx >= total) return;
  int j = idx % nW;
  int t = idx / nW;
  int i = t % nH;
  int b = t / nH;
  if (((i + j) & 1) == 0) return;
  const float* base = img + (size_t)b * nH * nW;
  float ssum = 0.0f;
  if (i > 0)      ssum += sk[1] * base[(i - 1) * nW + j];
  if (j > 0)      ssum += sk[3] * base[i * nW + j - 1];
  if (j < nW - 1) ssum += sk[5] * base[i * nW + j + 1];
  if (i < nH - 1) ssum += sk[7] * base[(i + 1) * nW + j];
  // denom = conv3(ones, sk): sum of in-bounds kernel weights
  float denom = 0.0f;
#pragma unroll
  for (int di = 0; di < 3; ++di) {
#pragma unroll
    for (int dj = 0; dj < 3; ++dj) {
      int ii = i + di - 1, jj = j + dj - 1;
      if (ii >= 0 && ii < nH && jj >= 0 && jj < nW) denom += sk[di * 3 + dj];
    }
  }
  float u = tf_unif(ks0, ks1, (uint32_t)idx);
  img[idx] = ssum / denom + (u - 0.5f) * scale_p[0];
}

extern "C" void kernel_launch(void* const* d_in, const int* in_sizes, int n_in,
                              void* d_out, int out_size, void* d_ws, size_t ws_size,
                              hipStream_t stream) {
  const float* img     = (const float*)d_in[0];
  const float* dk      = (const float*)d_in[1];
  const float* sk      = (const float*)d_in[2];
  const float* scale_p = (const float*)d_in[3];

  // derive starting H from in_sizes[0] = 4*H*H
  int H = (int)(sqrt((double)(in_sizes[0] / 4)) + 0.5);

  // derive step count from out_size = 4*Hf*Hf
  int steps = 0;
  {
    long long h = H;
    long long target = (long long)out_size / 4;
    while (h * h != target && steps < 12) { h = 2 * h - 1; steps++; }
  }

  if (steps == 0) {
    hipMemcpyAsync(d_out, (const void*)img, (size_t)out_size * sizeof(float),
                   hipMemcpyDeviceToDevice, stream);
    return;
  }

  // ping-pong scratch slots in d_ws (slot s%2 holds output of step s, s<steps-1)
  long long slotElems[2] = {0, 0};
  {
    long long h = H;
    for (int s = 0; s < steps - 1; ++s) {
      long long nh = 2 * h - 1;
      long long elems = 4 * nh * nh;
      if (elems > slotElems[s & 1]) slotElems[s & 1] = elems;
      h = nh;
    }
  }
  float* slot[2];
  slot[0] = (float*)d_ws;
  slot[1] = slot[0] + slotElems[0];

  const float* src = img;
  int h = H;
  for (int s = 0; s < steps; ++s) {
    int nH = 2 * h - 1;
    float* dst = (s == steps - 1) ? (float*)d_out : slot[s & 1];

    // host-side key derivation (JAX partitionable threefry):
    // fk = fold_in(key(42), s); kd = TF(fk,(0,0)); ks = TF(fk,(0,1))
    U2 fk = tf2x32(0u, 42u, 0u, (uint32_t)s);
    U2 kd = tf2x32(fk.a, fk.b, 0u, 0u);
    U2 ks = tf2x32(fk.a, fk.b, 0u, 1u);

    int total = 4 * nH * nH;
    int blocks = (total + 255) / 256;
    ds_k1<<<blocks, 256, 0, stream>>>(src, dst, h, h, nH, nH, dk, scale_p,
                                      kd.a, kd.b);
    ds_k2<<<blocks, 256, 0, stream>>>(dst, nH, nH, sk, scale_p, ks.a, ks.b);
    src = dst;
    h = nH;
  }
}

// Round 3
// 597.591 us; speedup vs baseline: 1.9118x; 1.9118x over previous
//
#include <hip/hip_runtime.h>
#include <stdint.h>
#include <math.h>

// ---------------- Threefry-2x32 (JAX-compatible, 20 rounds) ----------------
__host__ __device__ static inline uint32_t rotl32(uint32_t v, uint32_t d) {
  return (v << d) | (v >> (32u - d));
}

struct U2 { uint32_t a, b; };

__host__ __device__ static inline U2 tf2x32(uint32_t k0, uint32_t k1,
                                            uint32_t x0, uint32_t x1) {
  const uint32_t k2 = k0 ^ k1 ^ 0x1BD11BDAu;
  x0 += k0; x1 += k1;
#define TF_R(rot) { x0 += x1; x1 = rotl32(x1, rot); x1 ^= x0; }
  TF_R(13u) TF_R(15u) TF_R(26u) TF_R(6u)
  x0 += k1; x1 += k2 + 1u;
  TF_R(17u) TF_R(29u) TF_R(16u) TF_R(24u)
  x0 += k2; x1 += k0 + 2u;
  TF_R(13u) TF_R(15u) TF_R(26u) TF_R(6u)
  x0 += k0; x1 += k1 + 3u;
  TF_R(17u) TF_R(29u) TF_R(16u) TF_R(24u)
  x0 += k1; x1 += k2 + 4u;
  TF_R(13u) TF_R(15u) TF_R(26u) TF_R(6u)
  x0 += k2; x1 += k0 + 5u;
#undef TF_R
  U2 r; r.a = x0; r.b = x1; return r;
}

// Partitionable random bits: bits[i] = y0 ^ y1 of TF(key, (0, i));
// uniform[0,1): bitcast((bits>>9)|0x3f800000) - 1
__device__ static inline float tf_unif(uint32_t k0, uint32_t k1, uint32_t idx) {
  U2 r = tf2x32(k0, k1, 0u, idx);
  uint32_t bits = r.a ^ r.b;
  return __uint_as_float((bits >> 9) | 0x3f800000u) - 1.0f;
}

// ------------------- fused one-level diamond-square kernel ------------------
// Output tile: TOH x TOW per workgroup; LDS "val" tile holds new-grid values
// with a halo of 1 on all sides.
#define TOH 16
#define TOW 64

__global__ __launch_bounds__(256) void ds_fused(
    const float* __restrict__ src, float* __restrict__ dst,
    int H, int W, int nH, int nW,
    const float* __restrict__ dk, const float* __restrict__ sk,
    const float* __restrict__ scale_p,
    uint32_t kd0, uint32_t kd1, uint32_t ks0, uint32_t ks1)
{
  __shared__ float val[TOH + 2][TOW + 2];

  const int tid = threadIdx.x;
  const int b  = blockIdx.z;
  const int r0 = blockIdx.y * TOH;
  const int c0 = blockIdx.x * TOW;

  const float scale = scale_p[0];
  const float dk0 = dk[0], dk2 = dk[2], dk6 = dk[6], dk8 = dk[8];
  const float sk1 = sk[1], sk3 = sk[3], sk5 = sk[5], sk7 = sk[7];
  const float S9 = sk[0] + sk[1] + sk[2] + sk[3] + sk[4] + sk[5] + sk[6] +
                   sk[7] + sk[8];

  const float* srcb = src + (size_t)b * H * W;

  // ---- Phase C: all even-parity sites of the halo'd tile ----
  // rows li in [0,18), 33 even-parity cols per row -> 594 sites
  for (int t = tid; t < (TOH + 2) * ((TOW + 2) / 2); t += 256) {
    int li = t / 33;
    int k  = t - li * 33;
    int gi = r0 - 1 + li;
    int q  = (gi + c0 + 1) & 1;     // col parity so that (gi+gj) is even
    int lj = 2 * k + q;             // max 65 < TOW+2
    int gj = c0 - 1 + lj;
    float v = 0.0f;
    if (gi >= 0 && gi < nH && gj >= 0 && gj < nW) {
      if (((gi | gj) & 1) == 0) {
        // (even,even): copy old grid value
        v = srcb[(gi >> 1) * W + (gj >> 1)];
      } else {
        // (odd,odd): diamond = 4 diagonal taps of old grid + noise
        int rd = (gi - 1) >> 1, cd = (gj - 1) >> 1;
        const float* s0 = srcb + rd * W + cd;
        float conv = dk0 * s0[0] + dk2 * s0[1] + dk6 * s0[W] + dk8 * s0[W + 1];
        uint32_t nidx = (uint32_t)((b * (H - 1) + rd) * (W - 1) + cd);
        v = conv + (tf_unif(kd0, kd1, nidx) - 0.5f) * scale;
      }
    }
    val[li][lj] = v;
  }
  __syncthreads();

  // ---- Phase E1: square sites ((gi+gj) odd) inside the tile ----
  // dense mapping: 16 rows x 32 square sites/row = 512, no masked lanes
  for (int s = tid; s < TOH * (TOW / 2); s += 256) {
    int lr = s >> 5;
    int k  = s & 31;
    int gi = r0 + lr;
    int q  = (gi + c0 + 1) & 1;     // col parity so that (gi+gj) is odd
    int gj = c0 + 2 * k + q;
    if (gi < nH && gj < nW) {
      int li = lr + 1, lj = gj - c0 + 1;
      float ssum = sk1 * val[li - 1][lj] + sk3 * val[li][lj - 1] +
                   sk5 * val[li][lj + 1] + sk7 * val[li + 1][lj];
      float denom;
      if (gi > 0 && gi < nH - 1 && gj > 0 && gj < nW - 1) {
        denom = S9;                 // interior fast path
      } else {
        denom = 0.0f;
#pragma unroll
        for (int di = 0; di < 3; ++di) {
#pragma unroll
          for (int dj = 0; dj < 3; ++dj) {
            int ii = gi + di - 1, jj = gj + dj - 1;
            if (ii >= 0 && ii < nH && jj >= 0 && jj < nW)
              denom += sk[di * 3 + dj];
          }
        }
      }
      uint32_t nidx = (uint32_t)((b * nH + gi) * nW + gj);
      val[li][lj] = ssum / denom + (tf_unif(ks0, ks1, nidx) - 0.5f) * scale;
    }
  }
  __syncthreads();

  // ---- Phase E2: coalesced write-out of the whole tile ----
  float* dstb = dst + (size_t)b * nH * nW;
  for (int t = tid; t < TOH * TOW; t += 256) {
    int lr = t >> 6;
    int k  = t & 63;
    int gi = r0 + lr, gj = c0 + k;
    if (gi < nH && gj < nW) dstb[gi * nW + gj] = val[lr + 1][k + 1];
  }
}

extern "C" void kernel_launch(void* const* d_in, const int* in_sizes, int n_in,
                              void* d_out, int out_size, void* d_ws, size_t ws_size,
                              hipStream_t stream) {
  const float* img     = (const float*)d_in[0];
  const float* dk      = (const float*)d_in[1];
  const float* sk      = (const float*)d_in[2];
  const float* scale_p = (const float*)d_in[3];

  // derive starting H from in_sizes[0] = 4*H*H  (B=4, C=1, square)
  int H = (int)(sqrt((double)(in_sizes[0] / 4)) + 0.5);

  // derive step count from out_size = 4*Hf*Hf
  int steps = 0;
  {
    long long h = H;
    long long target = (long long)out_size / 4;
    while (h * h != target && steps < 12) { h = 2 * h - 1; steps++; }
  }

  if (steps == 0) {
    hipMemcpyAsync(d_out, (const void*)img, (size_t)out_size * sizeof(float),
                   hipMemcpyDeviceToDevice, stream);
    return;
  }

  // ping-pong scratch slots in d_ws (slot s%2 holds output of step s, s<steps-1)
  long long slotElems[2] = {0, 0};
  {
    long long h = H;
    for (int s = 0; s < steps - 1; ++s) {
      long long nh = 2 * h - 1;
      long long elems = 4 * nh * nh;
      if (elems > slotElems[s & 1]) slotElems[s & 1] = elems;
      h = nh;
    }
  }
  float* slot[2];
  slot[0] = (float*)d_ws;
  slot[1] = slot[0] + slotElems[0];

  const float* src = img;
  int h = H;
  for (int s = 0; s < steps; ++s) {
    int nH = 2 * h - 1;
    float* dst = (s == steps - 1) ? (float*)d_out : slot[s & 1];

    // host-side key derivation (JAX partitionable threefry):
    // fk = fold_in(key(42), s); kd = TF(fk,(0,0)); ks = TF(fk,(0,1))
    U2 fk = tf2x32(0u, 42u, 0u, (uint32_t)s);
    U2 kd = tf2x32(fk.a, fk.b, 0u, 0u);
    U2 ks = tf2x32(fk.a, fk.b, 0u, 1u);

    dim3 grid((nH + TOW - 1) / TOW, (nH + TOH - 1) / TOH, 4);
    ds_fused<<<grid, 256, 0, stream>>>(src, dst, h, h, nH, nH, dk, sk, scale_p,
                                       kd.a, kd.b, ks.a, ks.b);
    src = dst;
    h = nH;
  }
}

// Round 4
// 507.926 us; speedup vs baseline: 2.2493x; 1.1765x over previous
//
#include <hip/hip_runtime.h>
#include <stdint.h>
#include <math.h>

// ---------------- Threefry-2x32 (JAX-compatible, 20 rounds) ----------------
__host__ __device__ static inline uint32_t rotl32(uint32_t v, uint32_t d) {
  return (v << d) | (v >> (32u - d));
}

struct U2 { uint32_t a, b; };

__host__ __device__ static inline U2 tf2x32(uint32_t k0, uint32_t k1,
                                            uint32_t x0, uint32_t x1) {
  const uint32_t k2 = k0 ^ k1 ^ 0x1BD11BDAu;
  x0 += k0; x1 += k1;
#define TF_R(rot) { x0 += x1; x1 = rotl32(x1, rot); x1 ^= x0; }
  TF_R(13u) TF_R(15u) TF_R(26u) TF_R(6u)
  x0 += k1; x1 += k2 + 1u;
  TF_R(17u) TF_R(29u) TF_R(16u) TF_R(24u)
  x0 += k2; x1 += k0 + 2u;
  TF_R(13u) TF_R(15u) TF_R(26u) TF_R(6u)
  x0 += k0; x1 += k1 + 3u;
  TF_R(17u) TF_R(29u) TF_R(16u) TF_R(24u)
  x0 += k1; x1 += k2 + 4u;
  TF_R(13u) TF_R(15u) TF_R(26u) TF_R(6u)
  x0 += k2; x1 += k0 + 5u;
#undef TF_R
  U2 r; r.a = x0; r.b = x1; return r;
}

// Partitionable random bits: bits[i] = y0 ^ y1 of TF(key, (0, i));
// uniform[0,1): bitcast((bits>>9)|0x3f800000) - 1
__device__ static inline float tf_unif(uint32_t k0, uint32_t k1, uint32_t idx) {
  U2 r = tf2x32(k0, k1, 0u, idx);
  uint32_t bits = r.a ^ r.b;
  return __uint_as_float((bits >> 9) | 0x3f800000u) - 1.0f;
}

// ------------------- quad-per-thread fused level kernel ---------------------
// Thread (qi,qj) owns the 2x2 output block anchored at (2qi, 2qj):
//   E  = (2qi,   2qj)   copy of src[qi][qj]
//   D  = (2qi+1, 2qj+1) diamond (4 diag src taps + noise)
//   S1 = (2qi+1, 2qj)   square: N=E, W=D(qi,qj-1), E=D, S=E(qi+1,qj)
//   S2 = (2qi,   2qj+1) square: N=D(qi-1,qj), W=E, E=E(qi,qj+1), S=D
// E/D shared across quads via LDS (halo of 1 quad). Odd coordinates are never
// on the grid boundary, so S1 only loses the left/right kernel column and S2
// only the top/bottom kernel row -> cheap edge denominators.
#define QT 16
#define HQ (QT + 2)          // 18 halo'd quads per side
#define NHALO (HQ * HQ)      // 324

__global__ __launch_bounds__(256) void ds_quad(
    const float* __restrict__ src, float* __restrict__ dst,
    int H, int W, int nH, int nW,
    const float* __restrict__ dk, const float* __restrict__ sk,
    const float* __restrict__ scale_p,
    uint32_t kd0, uint32_t kd1, uint32_t ks0, uint32_t ks1)
{
  __shared__ float Eld[HQ][HQ + 1];
  __shared__ float Dld[HQ][HQ + 1];

  const int tid = threadIdx.x;
  const int b   = blockIdx.z;
  const int q0i = blockIdx.y * QT;
  const int q0j = blockIdx.x * QT;

  const float scale = scale_p[0];
  const float dk0 = dk[0], dk2 = dk[2], dk6 = dk[6], dk8 = dk[8];
  const float sk1 = sk[1], sk3 = sk[3], sk5 = sk[5], sk7 = sk[7];
  const float S9   = sk[0]+sk[1]+sk[2]+sk[3]+sk[4]+sk[5]+sk[6]+sk[7]+sk[8];
  const float Ctop = sk[0]+sk[1]+sk[2];
  const float Cbot = sk[6]+sk[7]+sk[8];
  const float Clft = sk[0]+sk[3]+sk[6];
  const float Crgt = sk[2]+sk[5]+sk[8];
  const float rS9  = 1.0f / S9;

  const float* srcb = src + (size_t)b * H * W;

  // ---- Phase A: E and D for the halo'd 18x18 quad region ----
  for (int t = tid; t < NHALO; t += 256) {
    int lqi = t / HQ;
    int lqj = t - lqi * HQ;
    int qi = q0i - 1 + lqi;
    int qj = q0j - 1 + lqj;
    float E = 0.0f, D = 0.0f;
    if ((unsigned)qi < (unsigned)H && (unsigned)qj < (unsigned)W) {
      const float* s0 = srcb + qi * W + qj;
      E = s0[0];
      if (qi + 1 < H && qj + 1 < W) {
        float conv = dk0 * E + dk2 * s0[1] + dk6 * s0[W] + dk8 * s0[W + 1];
        uint32_t nidx = (uint32_t)((b * (H - 1) + qi) * (W - 1) + qj);
        D = conv + (tf_unif(kd0, kd1, nidx) - 0.5f) * scale;
      }
    }
    Eld[lqi][lqj] = E;
    Dld[lqi][lqj] = D;
  }
  __syncthreads();

  // ---- Phase B: squares + direct register->global write of the 2x2 block ---
  {
    const int ti = tid >> 4, tj = tid & 15;
    const int qi = q0i + ti, qj = q0j + tj;
    if (qi < H && qj < W) {
      const int lqi = ti + 1, lqj = tj + 1;
      const int gi = 2 * qi, gj = 2 * qj;
      const float E = Eld[lqi][lqj];
      const float D = Dld[lqi][lqj];
      const uint32_t base = (uint32_t)(gi * nW + gj);
      const uint32_t bOff = (uint32_t)b * (uint32_t)(nH * nW);
      float* dp = dst + ((size_t)bOff + base);
      dp[0] = E;
      const bool haveS = (gi + 1 < nH);
      const bool haveE = (gj + 1 < nW);
      if (haveS) {  // S1 at (gi+1, gj): rows odd -> never top/bottom edge
        float num = sk1 * E + sk3 * Dld[lqi][lqj - 1] + sk5 * D +
                    sk7 * Eld[lqi + 1][lqj];
        float inv = rS9;
        if (gj == 0)           inv = 1.0f / (S9 - Clft);
        else if (gj == nW - 1) inv = 1.0f / (S9 - Crgt);
        float u = tf_unif(ks0, ks1, bOff + base + (uint32_t)nW);
        dp[nW] = num * inv + (u - 0.5f) * scale;
      }
      if (haveE) {  // S2 at (gi, gj+1): cols odd -> never left/right edge
        float num = sk1 * Dld[lqi - 1][lqj] + sk3 * E +
                    sk5 * Eld[lqi][lqj + 1] + sk7 * D;
        float inv = rS9;
        if (gi == 0)           inv = 1.0f / (S9 - Ctop);
        else if (gi == nH - 1) inv = 1.0f / (S9 - Cbot);
        float u = tf_unif(ks0, ks1, bOff + base + 1u);
        dp[1] = num * inv + (u - 0.5f) * scale;
      }
      if (haveS && haveE) dp[nW + 1] = D;
    }
  }
}

extern "C" void kernel_launch(void* const* d_in, const int* in_sizes, int n_in,
                              void* d_out, int out_size, void* d_ws, size_t ws_size,
                              hipStream_t stream) {
  const float* img     = (const float*)d_in[0];
  const float* dk      = (const float*)d_in[1];
  const float* sk      = (const float*)d_in[2];
  const float* scale_p = (const float*)d_in[3];

  // derive starting H from in_sizes[0] = 4*H*H  (B=4, C=1, square)
  int H = (int)(sqrt((double)(in_sizes[0] / 4)) + 0.5);

  // derive step count from out_size = 4*Hf*Hf
  int steps = 0;
  {
    long long h = H;
    long long target = (long long)out_size / 4;
    while (h * h != target && steps < 12) { h = 2 * h - 1; steps++; }
  }

  if (steps == 0) {
    hipMemcpyAsync(d_out, (const void*)img, (size_t)out_size * sizeof(float),
                   hipMemcpyDeviceToDevice, stream);
    return;
  }

  // ping-pong scratch slots in d_ws (slot s%2 holds output of step s, s<steps-1)
  long long slotElems[2] = {0, 0};
  {
    long long h = H;
    for (int s = 0; s < steps - 1; ++s) {
      long long nh = 2 * h - 1;
      long long elems = 4 * nh * nh;
      if (elems > slotElems[s & 1]) slotElems[s & 1] = elems;
      h = nh;
    }
  }
  float* slot[2];
  slot[0] = (float*)d_ws;
  slot[1] = slot[0] + slotElems[0];

  const float* src = img;
  int h = H;
  for (int s = 0; s < steps; ++s) {
    int nH = 2 * h - 1;
    float* dst = (s == steps - 1) ? (float*)d_out : slot[s & 1];

    // host-side key derivation (JAX partitionable threefry):
    // fk = fold_in(key(42), s); kd = TF(fk,(0,0)); ks = TF(fk,(0,1))
    U2 fk = tf2x32(0u, 42u, 0u, (uint32_t)s);
    U2 kd = tf2x32(fk.a, fk.b, 0u, 0u);
    U2 ks = tf2x32(fk.a, fk.b, 0u, 1u);

    // one thread per quad; quads per side == h (old-grid side)
    dim3 grid((h + QT - 1) / QT, (h + QT - 1) / QT, 4);
    ds_quad<<<grid, 256, 0, stream>>>(src, dst, h, h, nH, nH, dk, sk, scale_p,
                                      kd.a, kd.b, ks.a, ks.b);
    src = dst;
    h = nH;
  }
}

// Round 6
// 448.315 us; speedup vs baseline: 2.5484x; 1.1330x over previous
//
#include <hip/hip_runtime.h>
#include <stdint.h>
#include <math.h>

// ---------------- Threefry-2x32 (JAX-compatible, 20 rounds) ----------------
__host__ __device__ static inline uint32_t rotl32(uint32_t v, uint32_t d) {
  return (v << d) | (v >> (32u - d));
}

struct U2 { uint32_t a, b; };

__host__ __device__ static inline U2 tf2x32(uint32_t k0, uint32_t k1,
                                            uint32_t x0, uint32_t x1) {
  const uint32_t k2 = k0 ^ k1 ^ 0x1BD11BDAu;
  x0 += k0; x1 += k1;
#define TF_R(rot) { x0 += x1; x1 = rotl32(x1, rot); x1 ^= x0; }
  TF_R(13u) TF_R(15u) TF_R(26u) TF_R(6u)
  x0 += k1; x1 += k2 + 1u;
  TF_R(17u) TF_R(29u) TF_R(16u) TF_R(24u)
  x0 += k2; x1 += k0 + 2u;
  TF_R(13u) TF_R(15u) TF_R(26u) TF_R(6u)
  x0 += k0; x1 += k1 + 3u;
  TF_R(17u) TF_R(29u) TF_R(16u) TF_R(24u)
  x0 += k1; x1 += k2 + 4u;
  TF_R(13u) TF_R(15u) TF_R(26u) TF_R(6u)
  x0 += k2; x1 += k0 + 5u;
#undef TF_R
  U2 r; r.a = x0; r.b = x1; return r;
}

__device__ static inline float tf_unif(uint32_t k0, uint32_t k1, uint32_t idx) {
  U2 r = tf2x32(k0, k1, 0u, idx);
  uint32_t bits = r.a ^ r.b;
  return __uint_as_float((bits >> 9) | 0x3f800000u) - 1.0f;
}

// 3 independent Threefry chains, hand-interleaved for ILP=3.
// chain 0 uses key A (diamond), chains 1,2 use key B (square).
__device__ static inline void tf3_unif(uint32_t a0, uint32_t a1,
                                       uint32_t b0, uint32_t b1,
                                       uint32_t i0, uint32_t i1, uint32_t i2,
                                       float& u0, float& u1, float& u2) {
  const uint32_t kA[3] = {a0, a1, a0 ^ a1 ^ 0x1BD11BDAu};
  const uint32_t kB[3] = {b0, b1, b0 ^ b1 ^ 0x1BD11BDAu};
  uint32_t x0[3], x1[3];
  x0[0] = kA[0]; x1[0] = i0 + kA[1];
  x0[1] = kB[0]; x1[1] = i1 + kB[1];
  x0[2] = kB[0]; x1[2] = i2 + kB[1];
#define RR3(rot) { \
  x0[0] += x1[0]; x1[0] = rotl32(x1[0], rot); x1[0] ^= x0[0]; \
  x0[1] += x1[1]; x1[1] = rotl32(x1[1], rot); x1[1] ^= x0[1]; \
  x0[2] += x1[2]; x1[2] = rotl32(x1[2], rot); x1[2] ^= x0[2]; }
#define INJ3(p, q, c) { \
  x0[0] += kA[p]; x1[0] += kA[q] + (c); \
  x0[1] += kB[p]; x1[1] += kB[q] + (c); \
  x0[2] += kB[p]; x1[2] += kB[q] + (c); }
  RR3(13u) RR3(15u) RR3(26u) RR3(6u)  INJ3(1, 2, 1u)
  RR3(17u) RR3(29u) RR3(16u) RR3(24u) INJ3(2, 0, 2u)
  RR3(13u) RR3(15u) RR3(26u) RR3(6u)  INJ3(0, 1, 3u)
  RR3(17u) RR3(29u) RR3(16u) RR3(24u) INJ3(1, 2, 4u)
  RR3(13u) RR3(15u) RR3(26u) RR3(6u)  INJ3(2, 0, 5u)
#undef RR3
#undef INJ3
  uint32_t m0 = x0[0] ^ x1[0], m1 = x0[1] ^ x1[1], m2 = x0[2] ^ x1[2];
  u0 = __uint_as_float((m0 >> 9) | 0x3f800000u) - 1.0f;
  u1 = __uint_as_float((m1 >> 9) | 0x3f800000u) - 1.0f;
  u2 = __uint_as_float((m2 >> 9) | 0x3f800000u) - 1.0f;
}

// ------------------- quad-per-thread fused level kernel ---------------------
// Thread (qi,qj) owns output 2x2 at (2qi,2qj): E=src copy, D=diamond,
// S1=(2qi+1,2qj), S2=(2qi,2qj+1). All E-taps of S1/S2 lie in the thread's own
// 2x2 src block; only D crosses threads -> single LDS array with top/left halo.
#define QT 16

struct LevelConsts {
  float dk0, dk2, dk6, dk8;
  float sk1, sk3, sk5, sk7;
  float S9, rS9, Ctop, Cbot, Clft, Crgt, scale;
};

template <bool EDGE>
__device__ static inline void level_body(
    const float* __restrict__ srcb, float* __restrict__ dst,
    int H, int W, int nH, int nW, int q0i, int q0j, int b,
    const LevelConsts& c,
    uint32_t kd0, uint32_t kd1, uint32_t ks0, uint32_t ks1,
    float (&Dld)[QT + 1][QT + 2]) {
  const int tid = threadIdx.x;
  const int ti = tid >> 4, tj = tid & 15;
  const int qi = q0i + ti, qj = q0j + tj;

  bool inq = true;
  float v00 = 0.0f, v01 = 0.0f, v10 = 0.0f, v11 = 0.0f;
  if (!EDGE) {
    const float* s0 = srcb + qi * W + qj;
    v00 = s0[0]; v01 = s0[1]; v10 = s0[W]; v11 = s0[W + 1];
  } else {
    inq = (qi < H) && (qj < W);
    bool jp = (qj + 1 < W), ip = (qi + 1 < H);
    if (inq) {
      const float* s0 = srcb + qi * W + qj;
      v00 = s0[0];
      if (jp) v01 = s0[1];
      if (ip) v10 = s0[W];
      if (ip && jp) v11 = s0[W + 1];
    }
  }

  const uint32_t bOff = (uint32_t)b * (uint32_t)(nH * nW);
  const uint32_t base = bOff + (uint32_t)(2 * qi) * (uint32_t)nW +
                        (uint32_t)(2 * qj);
  const uint32_t idxD = (uint32_t)((b * (H - 1) + qi) * (W - 1) + qj);

  float uD, uS1, uS2;
  tf3_unif(kd0, kd1, ks0, ks1, idxD, base + (uint32_t)nW, base + 1u,
           uD, uS1, uS2);

  float D = c.dk0 * v00 + c.dk2 * v01 + c.dk6 * v10 + c.dk8 * v11 +
            (uD - 0.5f) * c.scale;
  if (EDGE) {
    if (!(qi + 1 < H && qj + 1 < W)) D = 0.0f;  // no diamond at last row/col
  }
  Dld[ti + 1][tj + 1] = D;

  // halo D: top row (17) + left col (16) = 33 extra diamonds
  if (tid < 33) {
    int hqi, hqj, r, cc;
    if (tid < 17) { hqi = q0i - 1; hqj = q0j - 1 + tid; r = 0; cc = tid; }
    else          { hqi = q0i + (tid - 17); hqj = q0j - 1; r = tid - 16; cc = 0; }
    float Dh = 0.0f;
    bool ok = !EDGE || (hqi >= 0 && hqj >= 0 && hqi + 1 < H && hqj + 1 < W);
    if (ok) {
      const float* s0 = srcb + hqi * W + hqj;
      uint32_t nidx = (uint32_t)((b * (H - 1) + hqi) * (W - 1) + hqj);
      float u = tf_unif(kd0, kd1, nidx);
      Dh = c.dk0 * s0[0] + c.dk2 * s0[1] + c.dk6 * s0[W] + c.dk8 * s0[W + 1] +
           (u - 0.5f) * c.scale;
    }
    Dld[r][cc] = Dh;
  }
  __syncthreads();

  const float Dw = Dld[ti + 1][tj];      // D(qi, qj-1)
  const float Dn = Dld[ti][tj + 1];      // D(qi-1, qj)

  const float s1num = c.sk1 * v00 + c.sk3 * Dw + c.sk5 * D + c.sk7 * v10;
  const float s2num = c.sk1 * Dn + c.sk3 * v00 + c.sk5 * v01 + c.sk7 * D;

  if (!EDGE) {
    float* dp = dst + (size_t)base;
    dp[0]      = v00;
    dp[1]      = s2num * c.rS9 + (uS2 - 0.5f) * c.scale;
    dp[nW]     = s1num * c.rS9 + (uS1 - 0.5f) * c.scale;
    dp[nW + 1] = D;
  } else if (inq) {
    const bool haveS = (qi + 1 < H);
    const bool haveE = (qj + 1 < W);
    float* dp = dst + (size_t)base;
    dp[0] = v00;
    if (haveS) {  // S1 row is odd -> only left/right edge renorm possible
      float inv = c.rS9;
      int gj = 2 * qj;
      if (gj == 0)           inv = 1.0f / (c.S9 - c.Clft);
      else if (gj == nW - 1) inv = 1.0f / (c.S9 - c.Crgt);
      dp[nW] = s1num * inv + (uS1 - 0.5f) * c.scale;
    }
    if (haveE) {  // S2 col is odd -> only top/bottom edge renorm possible
      float inv = c.rS9;
      int gi = 2 * qi;
      if (gi == 0)           inv = 1.0f / (c.S9 - c.Ctop);
      else if (gi == nH - 1) inv = 1.0f / (c.S9 - c.Cbot);
      dp[1] = s2num * inv + (uS2 - 0.5f) * c.scale;
    }
    if (haveS && haveE) dp[nW + 1] = D;
  }
}

__global__ __launch_bounds__(256) void ds_quad2(
    const float* __restrict__ src, float* __restrict__ dst,
    int H, int W, int nH, int nW,
    const float* __restrict__ dk, const float* __restrict__ sk,
    const float* __restrict__ scale_p,
    uint32_t kd0, uint32_t kd1, uint32_t ks0, uint32_t ks1) {
  __shared__ float Dld[QT + 1][QT + 2];

  const int b   = blockIdx.z;
  const int q0i = blockIdx.y * QT;
  const int q0j = blockIdx.x * QT;

  LevelConsts c;
  c.dk0 = dk[0]; c.dk2 = dk[2]; c.dk6 = dk[6]; c.dk8 = dk[8];
  c.sk1 = sk[1]; c.sk3 = sk[3]; c.sk5 = sk[5]; c.sk7 = sk[7];
  c.S9  = sk[0] + sk[1] + sk[2] + sk[3] + sk[4] + sk[5] + sk[6] + sk[7] + sk[8];
  c.rS9 = 1.0f / c.S9;
  c.Ctop = sk[0] + sk[1] + sk[2];
  c.Cbot = sk[6] + sk[7] + sk[8];
  c.Clft = sk[0] + sk[3] + sk[6];
  c.Crgt = sk[2] + sk[5] + sk[8];
  c.scale = scale_p[0];

  const float* srcb = src + (size_t)b * H * W;

  const bool interior = (q0i >= 1) && (q0j >= 1) &&
                        (q0i + QT < H) && (q0j + QT < W);
  if (interior)
    level_body<false>(srcb, dst, H, W, nH, nW, q0i, q0j, b, c,
                      kd0, kd1, ks0, ks1, Dld);
  else
    level_body<true>(srcb, dst, H, W, nH, nW, q0i, q0j, b, c,
                     kd0, kd1, ks0, ks1, Dld);
}

extern "C" void kernel_launch(void* const* d_in, const int* in_sizes, int n_in,
                              void* d_out, int out_size, void* d_ws, size_t ws_size,
                              hipStream_t stream) {
  const float* img     = (const float*)d_in[0];
  const float* dk      = (const float*)d_in[1];
  const float* sk      = (const float*)d_in[2];
  const float* scale_p = (const float*)d_in[3];

  // derive starting H from in_sizes[0] = 4*H*H  (B=4, C=1, square)
  int H = (int)(sqrt((double)(in_sizes[0] / 4)) + 0.5);

  // derive step count from out_size = 4*Hf*Hf
  int steps = 0;
  {
    long long h = H;
    long long target = (long long)out_size / 4;
    while (h * h != target && steps < 12) { h = 2 * h - 1; steps++; }
  }

  if (steps == 0) {
    hipMemcpyAsync(d_out, (const void*)img, (size_t)out_size * sizeof(float),
                   hipMemcpyDeviceToDevice, stream);
    return;
  }

  // ping-pong scratch slots in d_ws (slot s%2 holds output of step s, s<steps-1)
  long long slotElems[2] = {0, 0};
  {
    long long h = H;
    for (int s = 0; s < steps - 1; ++s) {
      long long nh = 2 * h - 1;
      long long elems = 4 * nh * nh;
      if (elems > slotElems[s & 1]) slotElems[s & 1] = elems;
      h = nh;
    }
  }
  float* slot[2];
  slot[0] = (float*)d_ws;
  slot[1] = slot[0] + slotElems[0];

  const float* src = img;
  int h = H;
  for (int s = 0; s < steps; ++s) {
    int nH = 2 * h - 1;
    float* dst = (s == steps - 1) ? (float*)d_out : slot[s & 1];

    // host-side key derivation (JAX partitionable threefry):
    // fk = fold_in(key(42), s); kd = TF(fk,(0,0)); ks = TF(fk,(0,1))
    U2 fk = tf2x32(0u, 42u, 0u, (uint32_t)s);
    U2 kd = tf2x32(fk.a, fk.b, 0u, 0u);
    U2 ks = tf2x32(fk.a, fk.b, 0u, 1u);

    // one thread per quad; quads per side == h (old-grid side)
    dim3 grid((h + QT - 1) / QT, (h + QT - 1) / QT, 4);
    ds_quad2<<<grid, 256, 0, stream>>>(src, dst, h, h, nH, nH, dk, sk, scale_p,
                                       kd.a, kd.b, ks.a, ks.b);
    src = dst;
    h = nH;
  }
}